// Round 9
// baseline (654.606 us; speedup 1.0000x reference)
//
#include <hip/hip_runtime.h>
#include <utility>
#include <cstddef>

// ---------------- compile-time Ivanic-Ruedenberg tables ----------------

struct Term { int o; int r; int a; float c; };
struct LTable { int n; Term t[1024]; };

constexpr double csqrt(double x) {
    if (x <= 0.0) return 0.0;
    double g = x < 1.0 ? 1.0 : x;
    for (int i = 0; i < 50; ++i) g = 0.5 * (g + x / g);
    return g;
}
constexpr int cabs_i(int x) { return x < 0 ? -x : x; }
constexpr int cmax_i(int a, int b) { return a > b ? a : b; }

constexpr void add_p(LTable& T, int o, double scale, int i, int a, int b, int l) {
    int lp = l - 1;
    int np = 2 * lp + 1;
    int row = i + 1;
    if (b == l) {
        T.t[T.n++] = Term{o, row * 3 + 2, (a + lp) * np + 2 * lp, (float)scale};
        T.t[T.n++] = Term{o, row * 3 + 0, (a + lp) * np + 0,      (float)(-scale)};
    } else if (b == -l) {
        T.t[T.n++] = Term{o, row * 3 + 2, (a + lp) * np + 0,      (float)scale};
        T.t[T.n++] = Term{o, row * 3 + 0, (a + lp) * np + 2 * lp, (float)scale};
    } else {
        T.t[T.n++] = Term{o, row * 3 + 1, (a + lp) * np + (b + lp), (float)scale};
    }
}

constexpr LTable ru_table(int l) {
    LTable T{};
    int n = 2 * l + 1;
    for (int m = -l; m <= l; ++m) {
        for (int mp = -l; mp <= l; ++mp) {
            double denom = (cabs_i(mp) == l) ? (double)((2 * l) * (2 * l - 1))
                                             : (double)((l + mp) * (l - mp));
            double d0 = (m == 0) ? 1.0 : 0.0;
            double u = csqrt((double)((l + m) * (l - m)) / denom);
            double v = 0.5 * csqrt((1.0 + d0) * (l + cabs_i(m) - 1) * (l + cabs_i(m)) / denom)
                       * (1.0 - 2.0 * d0);
            double w = -0.5 * csqrt((double)cmax_i(l - cabs_i(m) - 1, 0) * (l - cabs_i(m)) / denom)
                       * (1.0 - d0);
            int o = (m + l) * n + (mp + l);
            if (u != 0.0) add_p(T, o, u, 0, m, mp, l);
            if (v != 0.0) {
                if (m == 0) {
                    add_p(T, o, v, 1, 1, mp, l);
                    add_p(T, o, v, -1, -1, mp, l);
                } else if (m > 0) {
                    double s = (m == 1) ? csqrt(2.0) : 1.0;
                    add_p(T, o, v * s, 1, m - 1, mp, l);
                    if (m != 1) add_p(T, o, -v, -1, -m + 1, mp, l);
                } else {
                    if (m != -1) add_p(T, o, v, 1, m + 1, mp, l);
                    double s = (m == -1) ? csqrt(2.0) : 1.0;
                    add_p(T, o, v * s, -1, -m - 1, mp, l);
                }
            }
            if (w != 0.0) {
                if (m > 0) {
                    add_p(T, o, w, 1, m + 1, mp, l);
                    add_p(T, o, w, -1, -m - 1, mp, l);
                } else {
                    add_p(T, o, w, 1, m - 1, mp, l);
                    add_p(T, o, -w, -1, -m + 1, mp, l);
                }
            }
        }
    }
    return T;
}

inline constexpr LTable T2 = ru_table(2);
inline constexpr LTable T3 = ru_table(3);
inline constexpr LTable T4 = ru_table(4);

template<const LTable& T>
constexpr int er_start(int e) {
    for (int i = 0; i < T.n; ++i) if (T.t[i].o == e) return i;
    return 0;
}
template<const LTable& T>
constexpr int er_cnt(int e) {
    int c = 0;
    for (int i = 0; i < T.n; ++i) if (T.t[i].o == e) ++c;
    return c;
}

// ---------------- compact layout ----------------
// 165 nonzero slots per point: slot(l, e) = CBASE[l] + e, e flat within the
// (2l+1)^2 block; slot 165 is a guaranteed 0.0f pad (zero source for the
// expander); row stride CROW = 172 floats (688 B, 16B-multiple).
constexpr int CROW = 172;

// ---------------- recurrence (registers -> LDS row) ----------------

template<const LTable& T, int S, size_t... K>
__device__ __forceinline__ float sum_terms(const float* __restrict__ R1,
                                           const float* __restrict__ P,
                                           std::index_sequence<K...>) {
    float a = 0.0f;
    ((a = fmaf(T.t[S + (int)K].c, R1[T.t[S + (int)K].r] * P[T.t[S + (int)K].a], a)), ...);
    return a;
}

template<const LTable& T, int l, bool KEEP, bool COMPACT, int e>
__device__ __forceinline__ void level_one(const float* __restrict__ R1,
                                          const float* __restrict__ P,
                                          float* __restrict__ keep,
                                          float* __restrict__ row) {
    constexpr int S = er_start<T>(e);
    constexpr int C = er_cnt<T>(e);
    float v = sum_terms<T, S>(R1, P, std::make_index_sequence<C>{});
    if constexpr (KEEP) keep[e] = v;
    constexpr int d = 2 * l + 1;
    constexpr int CB = l == 0 ? 0 : l == 1 ? 1 : l == 2 ? 10 : l == 3 ? 35 : 84;
    constexpr int OFF = COMPACT ? (CB + e)
                                : ((l * l + e / d) * 25 + (l * l + e % d));
    row[OFF] = v;
}

template<const LTable& T, int l, bool KEEP, bool COMPACT, size_t... E>
__device__ __forceinline__ void level(const float* __restrict__ R1,
                                      const float* __restrict__ P,
                                      float* __restrict__ keep,
                                      float* __restrict__ row,
                                      std::index_sequence<E...>) {
    (level_one<T, l, KEEP, COMPACT, (int)E>(R1, P, keep, row), ...);
}

template<bool COMPACT, size_t... E>
__device__ __forceinline__ void write_l1(const float* __restrict__ D1,
                                         float* __restrict__ row,
                                         std::index_sequence<E...>) {
    ((row[COMPACT ? (1 + (int)E)
                  : ((1 + (int)E / 3) * 25 + (1 + (int)E % 3))] = D1[E]), ...);
}

// one point's full D streamed into an LDS row (compact or 625 layout)
template<bool COMPACT>
__device__ __forceinline__ void scatter_row(float ct, float st, float cp, float sp,
                                            float* __restrict__ row) {
    row[0] = 1.0f;                       // l=0
    if constexpr (COMPACT) row[165] = 0.0f;  // zero-source pad slot
    // R1 in real-SH l=1 basis order (y,z,x), row-major 3x3
    float D1[9] = {cp,      0.0f, -sp,
                   st * sp, ct,   st * cp,
                   ct * sp, -st,  ct * cp};
    write_l1<COMPACT>(D1, row, std::make_index_sequence<9>{});
    float D2[25];
    level<T2, 2, true, COMPACT>(D1, D1, D2, row, std::make_index_sequence<25>{});
    float D3[49];
    level<T3, 3, true, COMPACT>(D1, D2, D3, row, std::make_index_sequence<49>{});
    level<T4, 4, false, COMPACT>(D1, D3, nullptr, row, std::make_index_sequence<81>{});
}

typedef float v4f __attribute__((ext_vector_type(4)));

// lgkm-only barrier (proven neutral-or-better vs __syncthreads, R4 A/B)
__device__ __forceinline__ void bar_lgkm() {
    asm volatile("s_waitcnt lgkmcnt(0)" ::: "memory");
    __builtin_amdgcn_s_barrier();
    asm volatile("" ::: "memory");
}

// ---------------- kernel A: compact producer ----------------
// R5's proven scatter/copy skeleton with the image shrunk 625 -> 172 cols:
// LDS 32 x 172 floats = 22,016 B. Scatter: same recurrence, compile-time
// compact offsets. Copy: 1376 v4f contiguous to ws. Writes 138 MB instead
// of 500 MB; the 625-expansion moves to kernel B.

__global__ __launch_bounds__(256, 2)
void wigner_compact_kernel(const float* __restrict__ xyz, float* __restrict__ ws, int Ntot) {
    __shared__ __align__(16) float img[32 * CROW];

    const int t = threadIdx.x;
    const int gp = blockIdx.x * 256 + t;

    float x = 0.0f, y = 0.0f, z = 1.0f;
    if (gp < Ntot) {
        x = xyz[3 * gp + 0];
        y = xyz[3 * gp + 1];
        z = xyz[3 * gp + 2];
    }
    const float r2 = x * x + y * y + z * z;
    const float rinv = rsqrtf(fmaxf(r2, 1e-24f));
    const float ct = fminf(fmaxf(z * rinv, -1.0f), 1.0f);
    const float st = sqrtf(fmaxf(1.0f - ct * ct, 0.0f));
    const float rxy2 = x * x + y * y;
    float cp = 1.0f, sp = 0.0f;
    if (rxy2 > 0.0f) {
        const float ri = rsqrtf(rxy2);
        cp = x * ri;
        sp = y * ri;
    }

    const int p0 = t & 31;

    for (int c = 0; c < 8; ++c) {
        const int base_pt = blockIdx.x * 256 + c * 32;
        if (base_pt >= Ntot) break;  // uniform across block
        const int vp = min(32, Ntot - base_pt);

        if ((t >> 5) == c && gp < Ntot) {
            scatter_row<true>(ct, st, cp, sp, img + p0 * CROW);
        }
        bar_lgkm();  // scatter visible

        float* __restrict__ dstf = ws + (long long)base_pt * CROW;
        if (vp == 32) {
            const v4f* __restrict__ src = (const v4f*)img;
            v4f* __restrict__ dst = (v4f*)dstf;
#pragma unroll 3
            for (int k = t; k < 8 * CROW; k += 256) dst[k] = src[k];  // 1376 v4f
        } else {
            const int vf = vp * CROW;
            for (int k = t; k < vf; k += 256) dstf[k] = img[k];
        }
        bar_lgkm();  // copy reads retired before next scatter overwrites
    }
}

// ---------------- kernel B: fill-like expander ----------------
// One wave per point (grid-strided). The 10 per-lane compact-slot offsets
// are computed ARITHMETICALLY in the prologue (~40 VALU once per launch; no
// module-scope device objects). Per point: 10 gathers inside the point's
// 688 B compact row (L1-resident after first touch; structural zeros read
// the guaranteed-0.0f pad slot 165) and 10 wave-contiguous 256 B stores
// covering the full 2500 B output row. No LDS, no barriers, ~32 VGPR:
// structurally the same shape as the 6.2 TB/s fill kernel.

__device__ __forceinline__ int lof_d(int R) {
    return R >= 16 ? 4 : R >= 9 ? 3 : R >= 4 ? 2 : R >= 1 ? 1 : 0;
}

__global__ __launch_bounds__(256)
void expand_kernel(const float* __restrict__ ws, float* __restrict__ out, int Ntot) {
    const int lane = threadIdx.x & 63;
    const int wid = (blockIdx.x * 256 + threadIdx.x) >> 6;
    const int nw = (gridDim.x * 256) >> 6;

    const int cbase[5] = {0, 1, 10, 35, 84};
    int off[10];
#pragma unroll
    for (int j = 0; j < 10; ++j) {
        const int k = lane + 64 * j;
        int slot = 165;                       // structural zero / out-of-range
        if (k < 625) {
            const int R = k / 25, C = k % 25;
            const int lR = lof_d(R), lC = lof_d(C);
            if (lR == lC) {
                slot = cbase[lR] + (R - lR * lR) * (2 * lR + 1) + (C - lR * lR);
            }
        }
        off[j] = slot * 4;                    // byte offset into compact row
    }

    for (long long p = wid; p < Ntot; p += nw) {
        const char* __restrict__ src = (const char*)(ws + p * CROW);
        float* __restrict__ dst = out + p * 625;
#pragma unroll
        for (int j = 0; j < 10; ++j) {
            const float v = *(const float*)(src + off[j]);
            if (lane + 64 * j < 625) dst[lane + 64 * j] = v;  // j==9 partially masked
        }
    }
}

// ---------------- fallback: R5 fused kernel (best known single-pass) ----------------

__global__ __launch_bounds__(256, 2)
void wigner_fused_kernel(const float* __restrict__ xyz, float* __restrict__ out, int Ntot) {
    __shared__ float img[32 * 625];

    const int t = threadIdx.x;
    const int gp = blockIdx.x * 256 + t;

    float x = 0.0f, y = 0.0f, z = 1.0f;
    if (gp < Ntot) {
        x = xyz[3 * gp + 0];
        y = xyz[3 * gp + 1];
        z = xyz[3 * gp + 2];
    }
    const float r2 = x * x + y * y + z * z;
    const float rinv = rsqrtf(fmaxf(r2, 1e-24f));
    const float ct = fminf(fmaxf(z * rinv, -1.0f), 1.0f);
    const float st = sqrtf(fmaxf(1.0f - ct * ct, 0.0f));
    const float rxy2 = x * x + y * y;
    float cp = 1.0f, sp = 0.0f;
    if (rxy2 > 0.0f) {
        const float ri = rsqrtf(rxy2);
        cp = x * ri;
        sp = y * ri;
    }

    v4f* b4 = (v4f*)img;
    const v4f z4 = {0.0f, 0.0f, 0.0f, 0.0f};
#pragma unroll 4
    for (int k = t; k < 5000; k += 256) b4[k] = z4;
    bar_lgkm();

    const int p0 = t & 31;
    const long long blk_f = (long long)blockIdx.x * 256 * 625;

    for (int c = 0; c < 8; ++c) {
        const int base_pt = blockIdx.x * 256 + c * 32;
        if (base_pt >= Ntot) break;
        const int vp = min(32, Ntot - base_pt);

        if ((t >> 5) == c && gp < Ntot) {
            scatter_row<false>(ct, st, cp, sp, img + p0 * 625);
        }
        bar_lgkm();

        const long long out_f = blk_f + (long long)c * 32 * 625;
        if (vp == 32) {
            const v4f* src = (const v4f*)img;
            v4f* dst = (v4f*)(out + out_f);
#pragma unroll 4
            for (int k = t; k < 5000; k += 256) dst[k] = src[k];
        } else {
            const int vf = vp * 625;
            for (int k = t; k < vf; k += 256) out[out_f + k] = img[k];
        }
        bar_lgkm();
    }
}

extern "C" void kernel_launch(void* const* d_in, const int* in_sizes, int n_in,
                              void* d_out, int out_size, void* d_ws, size_t ws_size,
                              hipStream_t stream) {
    const float* xyz = (const float*)d_in[0];
    float* out = (float*)d_out;
    const int N = in_sizes[0] / 3;
    const size_t need = (size_t)N * CROW * sizeof(float);  // 137.6 MB at N=200000

    if (d_ws != nullptr && ws_size >= need) {
        const int blocksA = (N + 255) / 256;
        hipLaunchKernelGGL(wigner_compact_kernel, dim3(blocksA), dim3(256), 0, stream,
                           xyz, (float*)d_ws, N);
        hipLaunchKernelGGL(expand_kernel, dim3(2048), dim3(256), 0, stream,
                           (const float*)d_ws, out, N);
    } else {
        const int blocks = (N + 255) / 256;
        hipLaunchKernelGGL(wigner_fused_kernel, dim3(blocks), dim3(256), 0, stream,
                           xyz, out, N);
    }
}